// Round 6
// baseline (266.057 us; speedup 1.0000x reference)
//
#include <hip/hip_runtime.h>
#include <cstdint>

typedef unsigned short u16;
typedef __attribute__((ext_vector_type(8))) short bf16x8;
typedef __attribute__((ext_vector_type(4))) float f32x4;

constexpr int B_  = 8;
constexpr int C_  = 128;
constexpr int T_  = 8;
constexpr int HW_ = 1024;
constexpr int P_  = T_ * HW_;   // 8192 positions per (b,c)
constexpr int F_  = 128;        // PAM feature dim (16 cq * 8 t)
constexpr int CT_ = C_ * T_;    // 1024

static __device__ __forceinline__ u16 f2bf(float f) {
    union { float f; unsigned u; } v; v.f = f;
    unsigned r = v.u + 0x7fffu + ((v.u >> 16) & 1u);   // RNE
    return (u16)(r >> 16);
}
static __device__ __forceinline__ float bf2f(u16 h) {
    union { unsigned u; float f; } v; v.u = ((unsigned)h) << 16;
    return v.f;
}

#define GLOAD16(src, dst)                                                     \
    __builtin_amdgcn_global_load_lds(                                         \
        (const __attribute__((address_space(1))) void*)(src),                 \
        (__attribute__((address_space(3))) void*)(dst), 16, 0, 0)

// ---------------------------------------------------------------------------
// Fused prep: xT[b][p][c]=bf16(x), xhi=bf16(x), xlo=bf16(x-hi) in [c][p];
// block (64, y==0) casts W -> Wall[160][128] bf16 + ball fp32.
// ---------------------------------------------------------------------------
__global__ __launch_bounds__(256)
void k_prep(const float* __restrict__ x, u16* __restrict__ xT,
            u16* __restrict__ xhi, u16* __restrict__ xlo,
            const float* __restrict__ Wq, const float* __restrict__ bq,
            const float* __restrict__ Wk, const float* __restrict__ bk,
            const float* __restrict__ Wv, const float* __restrict__ bv,
            u16* __restrict__ Wall, float* __restrict__ ball)
{
    const int tid = threadIdx.x;
    if (blockIdx.x == 64) {                 // W-cast block (b==0 only)
        if (blockIdx.y != 0) return;
        for (int i = tid; i < 20480; i += 256) {
            int oc = i >> 7, c = i & 127;
            float w;
            if (oc < 16)      w = Wq[oc * 128 + c];
            else if (oc < 32) w = Wk[(oc - 16) * 128 + c];
            else              w = Wv[(oc - 32) * 128 + c];
            Wall[i] = f2bf(w);
        }
        if (tid < 160) {
            float bb;
            if (tid < 16)      bb = bq[tid];
            else if (tid < 32) bb = bk[tid - 16];
            else               bb = bv[tid - 32];
            ball[tid] = bb;
        }
        return;
    }

    __shared__ char sy[32768];
    const int b  = blockIdx.y;
    const int p0 = blockIdx.x * 128;

    #pragma unroll
    for (int r = 0; r < 16; r++) {
        int lin = r * 256 + tid;
        int c = lin >> 5, j4 = (lin & 31) << 2;
        size_t gi = ((size_t)(b * C_ + c)) * P_ + p0 + j4;
        float4 xv = *(const float4*)&x[gi];
        float a4[4] = {xv.x, xv.y, xv.z, xv.w};
        ushort4 h, l;
        h.x = f2bf(a4[0]); h.y = f2bf(a4[1]);
        h.z = f2bf(a4[2]); h.w = f2bf(a4[3]);
        l.x = f2bf(a4[0] - bf2f(h.x)); l.y = f2bf(a4[1] - bf2f(h.y));
        l.z = f2bf(a4[2] - bf2f(h.z)); l.w = f2bf(a4[3] - bf2f(h.w));
        *(ushort4*)&xhi[gi] = h;
        *(ushort4*)&xlo[gi] = l;
        #pragma unroll
        for (int u = 0; u < 4; u++) {
            int pi = j4 + u;
            int byte = pi * 256 + ((c * 2) ^ (((pi >> 2) & 15) << 4));
            *(u16*)(sy + byte) = (u == 0) ? h.x : (u == 1) ? h.y
                               : (u == 2) ? h.z : h.w;
        }
    }
    __syncthreads();
    #pragma unroll
    for (int r = 0; r < 8; r++) {
        int lin = r * 256 + tid;
        int pi = lin >> 4, ci8 = (lin & 15) << 3;
        bf16x8 v = *(const bf16x8*)(sy + pi * 256 +
                                    ((ci8 * 2) ^ (((pi >> 2) & 15) << 4)));
        *(bf16x8*)&xT[((size_t)(b * P_ + p0 + pi)) * C_ + ci8] = v;
    }
}

// ---------------------------------------------------------------------------
// QKV via MFMA: out[oc][p] = Wall[oc][:] . xT[p][:] + ball[oc].
// ---------------------------------------------------------------------------
__global__ __launch_bounds__(256)
void k_qkv(const u16* __restrict__ xT, const u16* __restrict__ Wall,
           const float* __restrict__ ball,
           u16* __restrict__ qt, u16* __restrict__ kt, u16* __restrict__ v16)
{
    __shared__ char Ws[40960];                 // 160 rows x 256B
    const int b  = blockIdx.y;
    const int p0 = blockIdx.x * 128;
    const int tid = threadIdx.x, lane = tid & 63, w = tid >> 6;

    #pragma unroll
    for (int i = 0; i < 10; i++) {
        int ch  = w * 10 + i;                  // 0..39, 4 rows each
        int row = ch * 4 + (lane >> 4);
        int col = ((lane & 15) ^ (row & 7)) * 8;
        GLOAD16(Wall + row * 128 + col, Ws + ch * 1024);
    }

    const u16* Bb = xT + ((size_t)(b * P_ + p0 + w * 32)) * F_;
    bf16x8 bg[4][2];
    #pragma unroll
    for (int ks = 0; ks < 4; ks++)
        #pragma unroll
        for (int ni = 0; ni < 2; ni++)
            bg[ks][ni] = *(const bf16x8*)(Bb +
                (size_t)(ni * 16 + (lane & 15)) * F_ + ks * 32 + (lane >> 4) * 8);
    __syncthreads();

    f32x4 acc[10][2];
    #pragma unroll
    for (int mi = 0; mi < 10; mi++) {
        acc[mi][0] = (f32x4){0.f, 0.f, 0.f, 0.f};
        acc[mi][1] = (f32x4){0.f, 0.f, 0.f, 0.f};
    }

    #pragma unroll
    for (int mi = 0; mi < 10; mi++) {
        #pragma unroll
        for (int ks = 0; ks < 4; ks++) {
            int row  = mi * 16 + (lane & 15);
            int slot = (ks * 4 + (lane >> 4)) ^ (row & 7);
            bf16x8 af = *(const bf16x8*)(Ws + row * 256 + slot * 16);
            acc[mi][0] = __builtin_amdgcn_mfma_f32_16x16x32_bf16(
                af, bg[ks][0], acc[mi][0], 0, 0, 0);
            acc[mi][1] = __builtin_amdgcn_mfma_f32_16x16x32_bf16(
                af, bg[ks][1], acc[mi][1], 0, 0, 0);
        }
    }

    const int t      = p0 >> 10;
    const int hwbase = (p0 & 1023) + w * 32;
    #pragma unroll
    for (int mi = 0; mi < 10; mi++)
        #pragma unroll
        for (int ni = 0; ni < 2; ni++)
            #pragma unroll
            for (int r = 0; r < 4; r++) {
                int oc = mi * 16 + (lane >> 4) * 4 + r;
                int hw = hwbase + ni * 16 + (lane & 15);
                u16 bv16 = f2bf(acc[mi][ni][r] + ball[oc]);
                if (mi == 0)
                    qt[((size_t)b * HW_ + hw) * F_ + oc * 8 + t] = bv16;
                else if (mi == 1)
                    kt[((size_t)b * HW_ + hw) * F_ + (oc - 16) * 8 + t] = bv16;
                else
                    v16[((size_t)(b * C_ + oc - 32)) * P_ + t * HW_ + hw] = bv16;
            }
}

// ---------------------------------------------------------------------------
// Energy MFMA: E[b][n][m] = sum_f qt[b][n][f] * kt[b][m][f].  K=128 one shot.
// ---------------------------------------------------------------------------
__global__ __launch_bounds__(256)
void k_energy(const u16* __restrict__ qt, const u16* __restrict__ kt,
              float* __restrict__ E)
{
    __shared__ char As[32768];
    __shared__ char Bs[32768];
    const int b  = blockIdx.z;
    const int n0 = blockIdx.y * 128, m0 = blockIdx.x * 128;
    const int tid = threadIdx.x, lane = tid & 63, w = tid >> 6;
    const u16* qb = qt + (size_t)b * HW_ * F_;
    const u16* kb = kt + (size_t)b * HW_ * F_;

    #pragma unroll
    for (int i = 0; i < 8; i++) {
        int c    = w * 8 + i;
        int row  = c * 4 + (lane >> 4);
        int col  = ((lane & 15) ^ (row & 7)) * 8;
        GLOAD16(qb + (size_t)(n0 + row) * F_ + col, As + c * 1024);
        GLOAD16(kb + (size_t)(m0 + row) * F_ + col, Bs + c * 1024);
    }
    __syncthreads();

    const int wr = w >> 1, wc = w & 1;
    f32x4 acc[4][4];
    #pragma unroll
    for (int mi = 0; mi < 4; mi++)
        #pragma unroll
        for (int ni = 0; ni < 4; ni++) acc[mi][ni] = (f32x4){0.f, 0.f, 0.f, 0.f};

    #pragma unroll
    for (int ks = 0; ks < 4; ks++) {
        bf16x8 af[4], bg[4];
        #pragma unroll
        for (int mi = 0; mi < 4; mi++) {
            int row  = wr * 64 + mi * 16 + (lane & 15);
            int slot = (ks * 4 + (lane >> 4)) ^ (row & 7);
            af[mi] = *(const bf16x8*)(As + row * 256 + slot * 16);
            int rb  = wc * 64 + mi * 16 + (lane & 15);
            int sb  = (ks * 4 + (lane >> 4)) ^ (rb & 7);
            bg[mi] = *(const bf16x8*)(Bs + rb * 256 + sb * 16);
        }
        #pragma unroll
        for (int mi = 0; mi < 4; mi++)
            #pragma unroll
            for (int ni = 0; ni < 4; ni++)
                acc[mi][ni] = __builtin_amdgcn_mfma_f32_16x16x32_bf16(
                    af[mi], bg[ni], acc[mi][ni], 0, 0, 0);
    }

    float* Eb = E + (size_t)b * HW_ * HW_;
    #pragma unroll
    for (int mi = 0; mi < 4; mi++)
        #pragma unroll
        for (int ni = 0; ni < 4; ni++)
            #pragma unroll
            for (int r = 0; r < 4; r++)
                Eb[(size_t)(n0 + wr * 64 + mi * 16 + (lane >> 4) * 4 + r) * HW_
                   + m0 + wc * 64 + ni * 16 + (lane & 15)] = acc[mi][ni][r];
}

// ---------------------------------------------------------------------------
// Row softmax (fp32 in) -> bf16 attn out.
// ---------------------------------------------------------------------------
__global__ __launch_bounds__(256)
void k_softmax(const float* __restrict__ E, u16* __restrict__ A16)
{
    const float* e = E + (size_t)blockIdx.x * HW_;
    const int tid = threadIdx.x;
    float4 v = ((const float4*)e)[tid];
    float m = fmaxf(fmaxf(v.x, v.y), fmaxf(v.z, v.w));
    #pragma unroll
    for (int off = 32; off; off >>= 1) m = fmaxf(m, __shfl_xor(m, off));
    __shared__ float s1[4], s2[4];
    if ((tid & 63) == 0) s1[tid >> 6] = m;
    __syncthreads();
    m = fmaxf(fmaxf(s1[0], s1[1]), fmaxf(s1[2], s1[3]));
    v.x = __expf(v.x - m); v.y = __expf(v.y - m);
    v.z = __expf(v.z - m); v.w = __expf(v.w - m);
    float s = v.x + v.y + v.z + v.w;
    #pragma unroll
    for (int off = 32; off; off >>= 1) s += __shfl_xor(s, off);
    if ((tid & 63) == 0) s2[tid >> 6] = s;
    __syncthreads();
    s = s2[0] + s2[1] + s2[2] + s2[3];
    float inv = 1.0f / s;
    ushort4 pk;
    pk.x = f2bf(v.x * inv); pk.y = f2bf(v.y * inv);
    pk.z = f2bf(v.z * inv); pk.w = f2bf(v.w * inv);
    ((ushort4*)(A16 + (size_t)blockIdx.x * HW_))[tid] = pk;
}

// ---------------------------------------------------------------------------
// PV MFMA, 2-phase double-buffered, one barrier per K-step.
// pam16[b][ct][n] = bf16(gp * sum_m V[ct][m] * attn[n][m]).
// ---------------------------------------------------------------------------
__global__ __launch_bounds__(256)
void k_pv(const u16* __restrict__ v16, const u16* __restrict__ A16,
          const float* __restrict__ gamma_pam, u16* __restrict__ pam16)
{
    __shared__ char As[2][16384];
    __shared__ char Bs[2][16384];
    const int b   = blockIdx.z;
    const int ct0 = blockIdx.y * 128, n0 = blockIdx.x * 128;
    const int tid = threadIdx.x, lane = tid & 63, w = tid >> 6;
    const u16* vb = v16 + (size_t)b * CT_ * HW_;
    const u16* ab = A16 + (size_t)b * HW_ * HW_;

    const int s_row = (lane >> 3);
    const int s_col = ((lane & 7) ^ ((lane >> 3) & 7)) * 8;

    const int wr = w >> 1, wc = w & 1;
    f32x4 acc[4][4];
    #pragma unroll
    for (int mi = 0; mi < 4; mi++)
        #pragma unroll
        for (int ni = 0; ni < 4; ni++) acc[mi][ni] = (f32x4){0.f, 0.f, 0.f, 0.f};

    // prologue: stage tile 0
    #pragma unroll
    for (int i = 0; i < 4; i++) {
        int c = w * 4 + i;
        int row = c * 8 + s_row;
        GLOAD16(vb + (size_t)(ct0 + row) * HW_ + s_col, As[0] + c * 1024);
        GLOAD16(ab + (size_t)(n0  + row) * HW_ + s_col, Bs[0] + c * 1024);
    }
    __syncthreads();

    int cur = 0;
    for (int it = 0; it < 16; ++it) {
        if (it < 15) {                       // prefetch next tile into cur^1
            int mc = (it + 1) * 64;
            #pragma unroll
            for (int i = 0; i < 4; i++) {
                int c = w * 4 + i;
                int row = c * 8 + s_row;
                GLOAD16(vb + (size_t)(ct0 + row) * HW_ + mc + s_col,
                        As[cur ^ 1] + c * 1024);
                GLOAD16(ab + (size_t)(n0  + row) * HW_ + mc + s_col,
                        Bs[cur ^ 1] + c * 1024);
            }
        }
        const char* Ac = As[cur];
        const char* Bc = Bs[cur];
        #pragma unroll
        for (int ks = 0; ks < 2; ks++) {
            bf16x8 af[4], bg[4];
            #pragma unroll
            for (int mi = 0; mi < 4; mi++) {
                int row  = wr * 64 + mi * 16 + (lane & 15);
                int slot = (ks * 4 + (lane >> 4)) ^ (row & 7);
                af[mi] = *(const bf16x8*)(Ac + row * 128 + slot * 16);
                int rb  = wc * 64 + mi * 16 + (lane & 15);
                int sb  = (ks * 4 + (lane >> 4)) ^ (rb & 7);
                bg[mi] = *(const bf16x8*)(Bc + rb * 128 + sb * 16);
            }
            #pragma unroll
            for (int mi = 0; mi < 4; mi++)
                #pragma unroll
                for (int ni = 0; ni < 4; ni++)
                    acc[mi][ni] = __builtin_amdgcn_mfma_f32_16x16x32_bf16(
                        af[mi], bg[ni], acc[mi][ni], 0, 0, 0);
        }
        __syncthreads();   // drains vmcnt(0): prefetch complete; all reads done
        cur ^= 1;
    }

    const float gp = gamma_pam[0];
    u16* ob = pam16 + (size_t)b * CT_ * HW_;
    #pragma unroll
    for (int mi = 0; mi < 4; mi++)
        #pragma unroll
        for (int ni = 0; ni < 4; ni++)
            #pragma unroll
            for (int r = 0; r < 4; r++)
                ob[(size_t)(ct0 + wr * 64 + mi * 16 + (lane >> 4) * 4 + r) * HW_
                   + n0 + wc * 64 + ni * 16 + (lane & 15)] =
                    f2bf(gp * acc[mi][ni][r]);
}

// ---------------------------------------------------------------------------
// CAM gram via split-precision MFMA: hi.hi + hi.lo + lo.hi.
// ---------------------------------------------------------------------------
__global__ __launch_bounds__(256)
void k_cam_gram(const u16* __restrict__ xhi, const u16* __restrict__ xlo,
                float* __restrict__ part)
{
    __shared__ char Sh[32768];
    __shared__ char Sl[32768];
    const int b = blockIdx.y, ch = blockIdx.x;
    const int tid = threadIdx.x, lane = tid & 63, w = tid >> 6;
    const u16* hb = xhi + (size_t)b * C_ * P_;
    const u16* lb = xlo + (size_t)b * C_ * P_;

    f32x4 acc[8][2];
    #pragma unroll
    for (int mi = 0; mi < 8; mi++) {
        acc[mi][0] = (f32x4){0.f, 0.f, 0.f, 0.f};
        acc[mi][1] = (f32x4){0.f, 0.f, 0.f, 0.f};
    }

    for (int kc = 0; kc < 2; kc++) {
        int n0 = ch * 256 + kc * 128;
        #pragma unroll
        for (int i = 0; i < 8; i++) {
            int c4  = w * 8 + i;
            int row = c4 * 4 + (lane >> 4);
            int col = ((lane & 15) ^ (row & 7)) * 8;
            GLOAD16(hb + (size_t)row * P_ + n0 + col, Sh + c4 * 1024);
            GLOAD16(lb + (size_t)row * P_ + n0 + col, Sl + c4 * 1024);
        }
        __syncthreads();
        #pragma unroll
        for (int ks = 0; ks < 4; ks++) {
            bf16x8 bh[2], bl[2];
            #pragma unroll
            for (int ni = 0; ni < 2; ni++) {
                int rb = w * 32 + ni * 16 + (lane & 15);
                int sb = (ks * 4 + (lane >> 4)) ^ (rb & 7);
                bh[ni] = *(const bf16x8*)(Sh + rb * 256 + sb * 16);
                bl[ni] = *(const bf16x8*)(Sl + rb * 256 + sb * 16);
            }
            #pragma unroll
            for (int mi = 0; mi < 8; mi++) {
                int ra = mi * 16 + (lane & 15);
                int sa = (ks * 4 + (lane >> 4)) ^ (ra & 7);
                bf16x8 ah = *(const bf16x8*)(Sh + ra * 256 + sa * 16);
                bf16x8 al = *(const bf16x8*)(Sl + ra * 256 + sa * 16);
                #pragma unroll
                for (int ni = 0; ni < 2; ni++) {
                    acc[mi][ni] = __builtin_amdgcn_mfma_f32_16x16x32_bf16(
                        ah, bh[ni], acc[mi][ni], 0, 0, 0);
                    acc[mi][ni] = __builtin_amdgcn_mfma_f32_16x16x32_bf16(
                        ah, bl[ni], acc[mi][ni], 0, 0, 0);
                    acc[mi][ni] = __builtin_amdgcn_mfma_f32_16x16x32_bf16(
                        al, bh[ni], acc[mi][ni], 0, 0, 0);
                }
            }
        }
        __syncthreads();
    }

    float* pb = part + ((size_t)(b * 32 + ch)) * 16384;
    #pragma unroll
    for (int mi = 0; mi < 8; mi++)
        #pragma unroll
        for (int ni = 0; ni < 2; ni++)
            #pragma unroll
            for (int r = 0; r < 4; r++) {
                int c = mi * 16 + (lane >> 4) * 4 + r;
                int d = w * 32 + ni * 16 + (lane & 15);
                pb[c * 128 + d] = acc[mi][ni][r];
            }
}

// ---------------------------------------------------------------------------
// CAM reduce + negated softmax -> bf16, pre-scaled by gamma_cam.
// ---------------------------------------------------------------------------
__global__ __launch_bounds__(128)
void k_cam_reduce(const float* __restrict__ part,
                  const float* __restrict__ gamma_cam, u16* __restrict__ acam16)
{
    const int b = blockIdx.y, c = blockIdx.x;
    const int d = threadIdx.x;
    float s = 0.f;
    for (int ch = 0; ch < 32; ch++)
        s += part[(((size_t)(b * 32 + ch)) * C_ + c) * C_ + d];
    float mn = s;
    #pragma unroll
    for (int off = 32; off; off >>= 1) mn = fminf(mn, __shfl_xor(mn, off));
    __shared__ float m1[2], m2[2];
    if ((d & 63) == 0) m1[d >> 6] = mn;
    __syncthreads();
    mn = fminf(m1[0], m1[1]);
    float p = __expf(mn - s);
    float sum = p;
    #pragma unroll
    for (int off = 32; off; off >>= 1) sum += __shfl_xor(sum, off);
    if ((d & 63) == 0) m2[d >> 6] = sum;
    __syncthreads();
    sum = m2[0] + m2[1];
    acam16[((size_t)(b * C_ + c)) * C_ + d] = f2bf(gamma_cam[0] * p / sum);
}

__global__ __launch_bounds__(256)
void k_tim_gram(const float* __restrict__ x, float* __restrict__ e_t)
{
    const int b = blockIdx.y, c = blockIdx.x;
    const int tid = threadIdx.x;
    const float* xb = x + ((size_t)(b * C_ + c)) * P_;
    float acc[8][8] = {};
    for (int r = 0; r < 4; r++) {
        int hw = r * 256 + tid;
        float xv[8];
        #pragma unroll
        for (int t = 0; t < 8; t++) xv[t] = xb[t * HW_ + hw];
        #pragma unroll
        for (int t = 0; t < 8; t++)
            #pragma unroll
            for (int s2 = 0; s2 < 8; s2++)
                acc[t][s2] += xv[t] * xv[s2];
    }
    __shared__ float sm[4][64];
    const int lane = tid & 63, wid = tid >> 6;
    #pragma unroll
    for (int u = 0; u < 64; u++) {
        float vv = acc[u >> 3][u & 7];
        #pragma unroll
        for (int off = 32; off; off >>= 1) vv += __shfl_xor(vv, off);
        if (lane == 0) sm[wid][u] = vv;
    }
    __syncthreads();
    if (tid < 64) {
        float vv = sm[0][tid] + sm[1][tid] + sm[2][tid] + sm[3][tid];
        atomicAdd(&e_t[b * 64 + tid], vv);
    }
}

// ---------------------------------------------------------------------------
// X' = 3x + gt*(TIM t-mix of x) -> bf16. TIM softmax computed inline from e_t.
// ---------------------------------------------------------------------------
__global__ __launch_bounds__(256)
void k_xprime(const float* __restrict__ x, const float* __restrict__ e_t,
              const float* __restrict__ gamma_tim, u16* __restrict__ Xp)
{
    const int b = blockIdx.y, c = blockIdx.x;
    const size_t base = ((size_t)(b * C_ + c)) * P_;
    const int tid = threadIdx.x;
    const float gt = gamma_tim[0];

    float4 xv[8];
    #pragma unroll
    for (int t = 0; t < 8; t++)
        xv[t] = *(const float4*)&x[base + t * HW_ + tid * 4];

    #pragma unroll
    for (int t = 0; t < 8; t++) {
        float e[8];
        #pragma unroll
        for (int s = 0; s < 8; s++) e[s] = e_t[b * 64 + t * 8 + s];
        float mn = e[0];
        #pragma unroll
        for (int s = 1; s < 8; s++) mn = fminf(mn, e[s]);
        float p[8], sum = 0.f;
        #pragma unroll
        for (int s = 0; s < 8; s++) { p[s] = __expf(mn - e[s]); sum += p[s]; }
        float inv = gt / sum;

        float4 o = make_float4(3.f * xv[t].x, 3.f * xv[t].y,
                               3.f * xv[t].z, 3.f * xv[t].w);
        #pragma unroll
        for (int s = 0; s < 8; s++) {
            float wgt = p[s] * inv;
            o.x += wgt * xv[s].x; o.y += wgt * xv[s].y;
            o.z += wgt * xv[s].z; o.w += wgt * xv[s].w;
        }
        ushort4 pk;
        pk.x = f2bf(o.x); pk.y = f2bf(o.y); pk.z = f2bf(o.z); pk.w = f2bf(o.w);
        *(ushort4*)&Xp[base + t * HW_ + tid * 4] = pk;
    }
}

// ---------------------------------------------------------------------------
// CAM AV MFMA + final combine: out = pam16 + acam16 @ x + X'.  Single store.
// ---------------------------------------------------------------------------
__global__ __launch_bounds__(256)
void k_cam_av(const u16* __restrict__ acam16, const u16* __restrict__ xT,
              const u16* __restrict__ Xp, const u16* __restrict__ pam16,
              float* __restrict__ out)
{
    const int b  = blockIdx.y;
    const int p0 = blockIdx.x * 128;
    const int tid = threadIdx.x, lane = tid & 63, w = tid >> 6;

    const u16* Ab = acam16 + (size_t)b * C_ * C_;
    const u16* Bb = xT + ((size_t)(b * P_ + p0 + w * 32)) * C_;

    f32x4 acc[8][2];
    #pragma unroll
    for (int mi = 0; mi < 8; mi++) {
        acc[mi][0] = (f32x4){0.f, 0.f, 0.f, 0.f};
        acc[mi][1] = (f32x4){0.f, 0.f, 0.f, 0.f};
    }

    bf16x8 bg[4][2];
    #pragma unroll
    for (int ks = 0; ks < 4; ks++)
        #pragma unroll
        for (int ni = 0; ni < 2; ni++)
            bg[ks][ni] = *(const bf16x8*)(Bb +
                (size_t)(ni * 16 + (lane & 15)) * C_ + ks * 32 + (lane >> 4) * 8);

    #pragma unroll
    for (int mi = 0; mi < 8; mi++) {
        #pragma unroll
        for (int ks = 0; ks < 4; ks++) {
            bf16x8 af = *(const bf16x8*)(Ab +
                (size_t)(mi * 16 + (lane & 15)) * C_ + ks * 32 + (lane >> 4) * 8);
            acc[mi][0] = __builtin_amdgcn_mfma_f32_16x16x32_bf16(
                af, bg[ks][0], acc[mi][0], 0, 0, 0);
            acc[mi][1] = __builtin_amdgcn_mfma_f32_16x16x32_bf16(
                af, bg[ks][1], acc[mi][1], 0, 0, 0);
        }
    }

    const int tt = p0 >> 10;                  // block spans a single t
    float* ob = out + (size_t)b * C_ * P_;
    const u16* xp = Xp + (size_t)b * C_ * P_;
    const u16* pb = pam16 + (size_t)b * CT_ * HW_;
    #pragma unroll
    for (int mi = 0; mi < 8; mi++)
        #pragma unroll
        for (int ni = 0; ni < 2; ni++)
            #pragma unroll
            for (int r = 0; r < 4; r++) {
                int c = mi * 16 + (lane >> 4) * 4 + r;
                int p = p0 + w * 32 + ni * 16 + (lane & 15);
                int hw = p & 1023;
                size_t i = (size_t)c * P_ + p;
                float pam = bf2f(pb[((size_t)(c * 8 + tt)) * HW_ + hw]);
                ob[i] = pam + acc[mi][ni][r] + bf2f(xp[i]);
            }
}

// ---------------------------------------------------------------------------
extern "C" void kernel_launch(void* const* d_in, const int* in_sizes, int n_in,
                              void* d_out, int out_size, void* d_ws, size_t ws_size,
                              hipStream_t stream)
{
    (void)in_sizes; (void)n_in; (void)out_size; (void)ws_size;
    const float* x  = (const float*)d_in[0];
    const float* Wq = (const float*)d_in[1];
    const float* bq = (const float*)d_in[2];
    const float* Wk = (const float*)d_in[3];
    const float* bk = (const float*)d_in[4];
    const float* Wv = (const float*)d_in[5];
    const float* bv = (const float*)d_in[6];
    const float* gp = (const float*)d_in[7];
    const float* gc = (const float*)d_in[8];
    const float* gt = (const float*)d_in[9];
    float* out = (float*)d_out;
    char*  ws  = (char*)d_ws;

    const size_t MiB = 1u << 20;
    // live ranges (step = launch index below):
    u16*   xT     = (u16*)(ws + 0);           // 16 MiB [1 -> 10]
    u16*   v16    = (u16*)(ws + 16 * MiB);    // 16 MiB [2 -> 6]
    u16*   xhi    = (u16*)(ws + 32 * MiB);    // 16 MiB [1 -> 8]
    u16*   xlo    = (u16*)(ws + 48 * MiB);    // 16 MiB [1 -> 8]
    float* Ebuf   = (float*)(ws + 64 * MiB);  // 32 MiB [3 -> 4]
    float* part   = (float*)(ws + 64 * MiB);  //   alias [8 -> 9]
    u16*   pam16  = (u16*)(ws + 80 * MiB);    //   alias [6 -> 10]
    u16*   A16    = (u16*)(ws + 96 * MiB);    // 16 MiB [4 -> 6]
    u16*   Xp16   = (u16*)(ws + 96 * MiB);    //   alias [7 -> 10]
    u16*   qtb    = (u16*)(ws + 112 * MiB);   // 2 MiB  [2 -> 3]
    u16*   ktb    = (u16*)(ws + 114 * MiB);   // 2 MiB
    u16*   acam16 = (u16*)(ws + 116 * MiB);   // 32 KB
    u16*   Wall   = (u16*)(ws + 116 * MiB + 65536);
    float* ball   = (float*)(ws + 116 * MiB + 131072);
    float* etim   = (float*)(ws + 116 * MiB + 139264);

    hipMemsetAsync(etim, 0, 512 * sizeof(float), stream);

    k_prep      <<<dim3(65, 8),   256, 0, stream>>>(x, xT, xhi, xlo,          // 1
                                                    Wq, bq, Wk, bk, Wv, bv,
                                                    Wall, ball);
    k_qkv       <<<dim3(64, 8),   256, 0, stream>>>(xT, Wall, ball,           // 2
                                                    qtb, ktb, v16);
    k_energy    <<<dim3(8, 8, 8), 256, 0, stream>>>(qtb, ktb, Ebuf);          // 3
    k_softmax   <<<dim3(8192),    256, 0, stream>>>(Ebuf, A16);               // 4
    k_tim_gram  <<<dim3(128, 8),  256, 0, stream>>>(x, etim);                 // 5
    k_pv        <<<dim3(8, 8, 8), 256, 0, stream>>>(v16, A16, gp, pam16);     // 6
    k_xprime    <<<dim3(128, 8),  256, 0, stream>>>(x, etim, gt, Xp16);       // 7
    k_cam_gram  <<<dim3(32, 8),   256, 0, stream>>>(xhi, xlo, part);          // 8
    k_cam_reduce<<<dim3(128, 8),  128, 0, stream>>>(part, gc, acam16);        // 9
    k_cam_av    <<<dim3(64, 8),   256, 0, stream>>>(acam16, xT, Xp16,         // 10
                                                    pam16, out);
}

// Round 7
// 264.119 us; speedup vs baseline: 1.0073x; 1.0073x over previous
//
#include <hip/hip_runtime.h>
#include <cstdint>

typedef unsigned short u16;
typedef __attribute__((ext_vector_type(8))) short bf16x8;
typedef __attribute__((ext_vector_type(4))) float f32x4;

constexpr int B_  = 8;
constexpr int C_  = 128;
constexpr int T_  = 8;
constexpr int HW_ = 1024;
constexpr int P_  = T_ * HW_;   // 8192 positions per (b,c)
constexpr int F_  = 128;        // PAM feature dim (16 cq * 8 t)
constexpr int CT_ = C_ * T_;    // 1024

static __device__ __forceinline__ u16 f2bf(float f) {
    union { float f; unsigned u; } v; v.f = f;
    unsigned r = v.u + 0x7fffu + ((v.u >> 16) & 1u);   // RNE
    return (u16)(r >> 16);
}
static __device__ __forceinline__ float bf2f(u16 h) {
    union { unsigned u; float f; } v; v.u = ((unsigned)h) << 16;
    return v.f;
}

#define GLOAD16(src, dst)                                                     \
    __builtin_amdgcn_global_load_lds(                                         \
        (const __attribute__((address_space(1))) void*)(src),                 \
        (__attribute__((address_space(3))) void*)(dst), 16, 0, 0)

// ---------------------------------------------------------------------------
// TIM gram: e_t[b][t][s] += sum over (c,hw) of x[..t..] x[..s..].
// Block (0,0) additionally casts W -> Wall[160][128] bf16 (used by k_prep,
// which runs after this kernel in stream order).
// ---------------------------------------------------------------------------
__global__ __launch_bounds__(256)
void k_tim_gram(const float* __restrict__ x, float* __restrict__ e_t,
                const float* __restrict__ Wq, const float* __restrict__ Wk,
                const float* __restrict__ Wv, u16* __restrict__ Wall)
{
    const int b = blockIdx.y, c = blockIdx.x;
    const int tid = threadIdx.x;

    if (blockIdx.x == 0 && blockIdx.y == 0) {
        for (int i = tid; i < 20480; i += 256) {
            int oc = i >> 7, cc = i & 127;
            float wv;
            if (oc < 16)      wv = Wq[oc * 128 + cc];
            else if (oc < 32) wv = Wk[(oc - 16) * 128 + cc];
            else              wv = Wv[(oc - 32) * 128 + cc];
            Wall[i] = f2bf(wv);
        }
    }

    const float* xb = x + ((size_t)(b * C_ + c)) * P_;
    float acc[8][8] = {};
    for (int r = 0; r < 4; r++) {
        int hw = r * 256 + tid;
        float xv[8];
        #pragma unroll
        for (int t = 0; t < 8; t++) xv[t] = xb[t * HW_ + hw];
        #pragma unroll
        for (int t = 0; t < 8; t++)
            #pragma unroll
            for (int s2 = 0; s2 < 8; s2++)
                acc[t][s2] += xv[t] * xv[s2];
    }
    __shared__ float sm[4][64];
    const int lane = tid & 63, wid = tid >> 6;
    #pragma unroll
    for (int u = 0; u < 64; u++) {
        float vv = acc[u >> 3][u & 7];
        #pragma unroll
        for (int off = 32; off; off >>= 1) vv += __shfl_xor(vv, off);
        if (lane == 0) sm[wid][u] = vv;
    }
    __syncthreads();
    if (tid < 64) {
        float vv = sm[0][tid] + sm[1][tid] + sm[2][tid] + sm[3][tid];
        atomicAdd(&e_t[b * 64 + tid], vv);
    }
}

// ---------------------------------------------------------------------------
// Fused prep: per block (p0,b): xhi/xlo [c][p], xT [p][c] (bf16),
// AND q/k/v via MFMA directly from the LDS x-tile (B) and Wall (A).
// ---------------------------------------------------------------------------
__global__ __launch_bounds__(256)
void k_prep(const float* __restrict__ x, u16* __restrict__ xT,
            u16* __restrict__ xhi, u16* __restrict__ xlo,
            const u16* __restrict__ Wall,
            const float* __restrict__ bq, const float* __restrict__ bk,
            const float* __restrict__ bv,
            u16* __restrict__ qt, u16* __restrict__ kt, u16* __restrict__ v16)
{
    __shared__ char sy[32768];                 // [128 p][128 c] bf16, swizzled
    const int b  = blockIdx.y;
    const int p0 = blockIdx.x * 128;
    const int tid = threadIdx.x, lane = tid & 63, w = tid >> 6;

    #pragma unroll
    for (int r = 0; r < 16; r++) {
        int lin = r * 256 + tid;
        int c = lin >> 5, j4 = (lin & 31) << 2;
        size_t gi = ((size_t)(b * C_ + c)) * P_ + p0 + j4;
        float4 xv = *(const float4*)&x[gi];
        float a4[4] = {xv.x, xv.y, xv.z, xv.w};
        ushort4 h, l;
        h.x = f2bf(a4[0]); h.y = f2bf(a4[1]);
        h.z = f2bf(a4[2]); h.w = f2bf(a4[3]);
        l.x = f2bf(a4[0] - bf2f(h.x)); l.y = f2bf(a4[1] - bf2f(h.y));
        l.z = f2bf(a4[2] - bf2f(h.z)); l.w = f2bf(a4[3] - bf2f(h.w));
        *(ushort4*)&xhi[gi] = h;
        *(ushort4*)&xlo[gi] = l;
        #pragma unroll
        for (int u = 0; u < 4; u++) {
            int pi = j4 + u;
            int byte = pi * 256 + ((c * 2) ^ (((pi >> 2) & 15) << 4));
            *(u16*)(sy + byte) = (u == 0) ? h.x : (u == 1) ? h.y
                               : (u == 2) ? h.z : h.w;
        }
    }
    __syncthreads();

    // xT (K-contiguous in c) for cam_av
    #pragma unroll
    for (int r = 0; r < 8; r++) {
        int lin = r * 256 + tid;
        int pi = lin >> 4, ci8 = (lin & 15) << 3;
        bf16x8 v = *(const bf16x8*)(sy + pi * 256 +
                                    ((ci8 * 2) ^ (((pi >> 2) & 15) << 4)));
        *(bf16x8*)&xT[((size_t)(b * P_ + p0 + pi)) * C_ + ci8] = v;
    }

    // ---- QKV MFMA: A = Wall rows (global, L2-hot), B = sy tile ----
    bf16x8 bg[4][2];
    #pragma unroll
    for (int ks = 0; ks < 4; ks++)
        #pragma unroll
        for (int ni = 0; ni < 2; ni++) {
            int p  = w * 32 + ni * 16 + (lane & 15);
            int cb = (ks * 32 + (lane >> 4) * 8) * 2;     // byte col
            bg[ks][ni] = *(const bf16x8*)(sy + p * 256 +
                              (cb ^ (((p >> 2) & 15) << 4)));
        }

    f32x4 acc[10][2];
    #pragma unroll
    for (int mi = 0; mi < 10; mi++) {
        acc[mi][0] = (f32x4){0.f, 0.f, 0.f, 0.f};
        acc[mi][1] = (f32x4){0.f, 0.f, 0.f, 0.f};
    }

    #pragma unroll
    for (int mi = 0; mi < 10; mi++) {
        #pragma unroll
        for (int ks = 0; ks < 4; ks++) {
            bf16x8 af = *(const bf16x8*)(Wall + (mi * 16 + (lane & 15)) * 128
                                          + ks * 32 + (lane >> 4) * 8);
            acc[mi][0] = __builtin_amdgcn_mfma_f32_16x16x32_bf16(
                af, bg[ks][0], acc[mi][0], 0, 0, 0);
            acc[mi][1] = __builtin_amdgcn_mfma_f32_16x16x32_bf16(
                af, bg[ks][1], acc[mi][1], 0, 0, 0);
        }
    }

    const int t      = p0 >> 10;
    const int hwbase = (p0 & 1023) + w * 32;
    #pragma unroll
    for (int mi = 0; mi < 10; mi++)
        #pragma unroll
        for (int ni = 0; ni < 2; ni++)
            #pragma unroll
            for (int r = 0; r < 4; r++) {
                int oc = mi * 16 + (lane >> 4) * 4 + r;
                int hw = hwbase + ni * 16 + (lane & 15);
                float bias;
                if (mi == 0)      bias = bq[oc];
                else if (mi == 1) bias = bk[oc - 16];
                else              bias = bv[oc - 32];
                u16 bv16 = f2bf(acc[mi][ni][r] + bias);
                if (mi == 0)
                    qt[((size_t)b * HW_ + hw) * F_ + oc * 8 + t] = bv16;
                else if (mi == 1)
                    kt[((size_t)b * HW_ + hw) * F_ + (oc - 16) * 8 + t] = bv16;
                else
                    v16[((size_t)(b * C_ + oc - 32)) * P_ + t * HW_ + hw] = bv16;
            }
}

// ---------------------------------------------------------------------------
// Fused energy+softmax: block = 16 n-rows x 1024 m, E stays in registers.
// A16[b][n][m] = softmax_m(sum_f qt[n][f] kt[m][f]) in bf16.
// ---------------------------------------------------------------------------
__global__ __launch_bounds__(256)
void k_attn(const u16* __restrict__ qt, const u16* __restrict__ kt,
            u16* __restrict__ A16)
{
    const int b  = blockIdx.y;
    const int n0 = blockIdx.x * 16;
    const int tid = threadIdx.x, lane = tid & 63, w = tid >> 6;
    const u16* qb = qt + (size_t)b * HW_ * F_;
    const u16* kb = kt + (size_t)b * HW_ * F_;

    bf16x8 af[4];
    #pragma unroll
    for (int ks = 0; ks < 4; ks++)
        af[ks] = *(const bf16x8*)(qb + (size_t)(n0 + (lane & 15)) * F_
                                  + ks * 32 + (lane >> 4) * 8);

    f32x4 acc[16];
    #pragma unroll
    for (int j = 0; j < 16; j++) acc[j] = (f32x4){0.f, 0.f, 0.f, 0.f};

    #pragma unroll
    for (int j = 0; j < 16; j++) {
        const int m0 = w * 256 + j * 16;
        #pragma unroll
        for (int ks = 0; ks < 4; ks++) {
            bf16x8 bg = *(const bf16x8*)(kb + (size_t)(m0 + (lane & 15)) * F_
                                         + ks * 32 + (lane >> 4) * 8);
            acc[j] = __builtin_amdgcn_mfma_f32_16x16x32_bf16(
                af[ks], bg, acc[j], 0, 0, 0);
        }
    }

    __shared__ float red[4][16];
    // row max (rows (lane>>4)*4+r, cols spread over 16-lane group + 16 tiles)
    float rmax[4];
    #pragma unroll
    for (int r = 0; r < 4; r++) {
        float m = acc[0][r];
        #pragma unroll
        for (int j = 1; j < 16; j++) m = fmaxf(m, acc[j][r]);
        #pragma unroll
        for (int off = 1; off < 16; off <<= 1) m = fmaxf(m, __shfl_xor(m, off));
        rmax[r] = m;
    }
    if ((lane & 15) == 0)
        #pragma unroll
        for (int r = 0; r < 4; r++) red[w][(lane >> 4) * 4 + r] = rmax[r];
    __syncthreads();
    #pragma unroll
    for (int r = 0; r < 4; r++) {
        int row = (lane >> 4) * 4 + r;
        rmax[r] = fmaxf(fmaxf(red[0][row], red[1][row]),
                        fmaxf(red[2][row], red[3][row]));
    }
    __syncthreads();                           // before reusing red for sums

    float rsum[4];
    #pragma unroll
    for (int r = 0; r < 4; r++) {
        float s = 0.f;
        #pragma unroll
        for (int j = 0; j < 16; j++) {
            acc[j][r] = __expf(acc[j][r] - rmax[r]);
            s += acc[j][r];
        }
        #pragma unroll
        for (int off = 1; off < 16; off <<= 1) s += __shfl_xor(s, off);
        rsum[r] = s;
    }
    if ((lane & 15) == 0)
        #pragma unroll
        for (int r = 0; r < 4; r++) red[w][(lane >> 4) * 4 + r] = rsum[r];
    __syncthreads();

    u16* ob = A16 + ((size_t)b * HW_ + n0) * HW_;
    #pragma unroll
    for (int r = 0; r < 4; r++) {
        int row = (lane >> 4) * 4 + r;
        float inv = 1.0f / (red[0][row] + red[1][row] +
                            red[2][row] + red[3][row]);
        #pragma unroll
        for (int j = 0; j < 16; j++)
            ob[(size_t)row * HW_ + w * 256 + j * 16 + (lane & 15)] =
                f2bf(acc[j][r] * inv);
    }
}

// ---------------------------------------------------------------------------
// PV MFMA, 2-phase double-buffered, one barrier per K-step.
// pam16[b][ct][n] = bf16(gp * sum_m V[ct][m] * attn[n][m]).
// ---------------------------------------------------------------------------
__global__ __launch_bounds__(256)
void k_pv(const u16* __restrict__ v16, const u16* __restrict__ A16,
          const float* __restrict__ gamma_pam, u16* __restrict__ pam16)
{
    __shared__ char As[2][16384];
    __shared__ char Bs[2][16384];
    const int b   = blockIdx.z;
    const int ct0 = blockIdx.y * 128, n0 = blockIdx.x * 128;
    const int tid = threadIdx.x, lane = tid & 63, w = tid >> 6;
    const u16* vb = v16 + (size_t)b * CT_ * HW_;
    const u16* ab = A16 + (size_t)b * HW_ * HW_;

    const int s_row = (lane >> 3);
    const int s_col = ((lane & 7) ^ ((lane >> 3) & 7)) * 8;

    const int wr = w >> 1, wc = w & 1;
    f32x4 acc[4][4];
    #pragma unroll
    for (int mi = 0; mi < 4; mi++)
        #pragma unroll
        for (int ni = 0; ni < 4; ni++) acc[mi][ni] = (f32x4){0.f, 0.f, 0.f, 0.f};

    #pragma unroll
    for (int i = 0; i < 4; i++) {
        int c = w * 4 + i;
        int row = c * 8 + s_row;
        GLOAD16(vb + (size_t)(ct0 + row) * HW_ + s_col, As[0] + c * 1024);
        GLOAD16(ab + (size_t)(n0  + row) * HW_ + s_col, Bs[0] + c * 1024);
    }
    __syncthreads();

    int cur = 0;
    for (int it = 0; it < 16; ++it) {
        if (it < 15) {
            int mc = (it + 1) * 64;
            #pragma unroll
            for (int i = 0; i < 4; i++) {
                int c = w * 4 + i;
                int row = c * 8 + s_row;
                GLOAD16(vb + (size_t)(ct0 + row) * HW_ + mc + s_col,
                        As[cur ^ 1] + c * 1024);
                GLOAD16(ab + (size_t)(n0  + row) * HW_ + mc + s_col,
                        Bs[cur ^ 1] + c * 1024);
            }
        }
        const char* Ac = As[cur];
        const char* Bc = Bs[cur];
        #pragma unroll
        for (int ks = 0; ks < 2; ks++) {
            bf16x8 af[4], bg[4];
            #pragma unroll
            for (int mi = 0; mi < 4; mi++) {
                int row  = wr * 64 + mi * 16 + (lane & 15);
                int slot = (ks * 4 + (lane >> 4)) ^ (row & 7);
                af[mi] = *(const bf16x8*)(Ac + row * 128 + slot * 16);
                int rb  = wc * 64 + mi * 16 + (lane & 15);
                int sb  = (ks * 4 + (lane >> 4)) ^ (rb & 7);
                bg[mi] = *(const bf16x8*)(Bc + rb * 128 + sb * 16);
            }
            #pragma unroll
            for (int mi = 0; mi < 4; mi++)
                #pragma unroll
                for (int ni = 0; ni < 4; ni++)
                    acc[mi][ni] = __builtin_amdgcn_mfma_f32_16x16x32_bf16(
                        af[mi], bg[ni], acc[mi][ni], 0, 0, 0);
        }
        __syncthreads();
        cur ^= 1;
    }

    const float gp = gamma_pam[0];
    u16* ob = pam16 + (size_t)b * CT_ * HW_;
    #pragma unroll
    for (int mi = 0; mi < 4; mi++)
        #pragma unroll
        for (int ni = 0; ni < 4; ni++)
            #pragma unroll
            for (int r = 0; r < 4; r++)
                ob[(size_t)(ct0 + wr * 64 + mi * 16 + (lane >> 4) * 4 + r) * HW_
                   + n0 + wc * 64 + ni * 16 + (lane & 15)] =
                    f2bf(gp * acc[mi][ni][r]);
}

// ---------------------------------------------------------------------------
// CAM gram via split-precision MFMA: hi.hi + hi.lo + lo.hi.
// ---------------------------------------------------------------------------
__global__ __launch_bounds__(256)
void k_cam_gram(const u16* __restrict__ xhi, const u16* __restrict__ xlo,
                float* __restrict__ part)
{
    __shared__ char Sh[32768];
    __shared__ char Sl[32768];
    const int b = blockIdx.y, ch = blockIdx.x;
    const int tid = threadIdx.x, lane = tid & 63, w = tid >> 6;
    const u16* hb = xhi + (size_t)b * C_ * P_;
    const u16* lb = xlo + (size_t)b * C_ * P_;

    f32x4 acc[8][2];
    #pragma unroll
    for (int mi = 0; mi < 8; mi++) {
        acc[mi][0] = (f32x4){0.f, 0.f, 0.f, 0.f};
        acc[mi][1] = (f32x4){0.f, 0.f, 0.f, 0.f};
    }

    for (int kc = 0; kc < 2; kc++) {
        int n0 = ch * 256 + kc * 128;
        #pragma unroll
        for (int i = 0; i < 8; i++) {
            int c4  = w * 8 + i;
            int row = c4 * 4 + (lane >> 4);
            int col = ((lane & 15) ^ (row & 7)) * 8;
            GLOAD16(hb + (size_t)row * P_ + n0 + col, Sh + c4 * 1024);
            GLOAD16(lb + (size_t)row * P_ + n0 + col, Sl + c4 * 1024);
        }
        __syncthreads();
        #pragma unroll
        for (int ks = 0; ks < 4; ks++) {
            bf16x8 bh[2], bl[2];
            #pragma unroll
            for (int ni = 0; ni < 2; ni++) {
                int rb = w * 32 + ni * 16 + (lane & 15);
                int sb = (ks * 4 + (lane >> 4)) ^ (rb & 7);
                bh[ni] = *(const bf16x8*)(Sh + rb * 256 + sb * 16);
                bl[ni] = *(const bf16x8*)(Sl + rb * 256 + sb * 16);
            }
            #pragma unroll
            for (int mi = 0; mi < 8; mi++) {
                int ra = mi * 16 + (lane & 15);
                int sa = (ks * 4 + (lane >> 4)) ^ (ra & 7);
                bf16x8 ah = *(const bf16x8*)(Sh + ra * 256 + sa * 16);
                bf16x8 al = *(const bf16x8*)(Sl + ra * 256 + sa * 16);
                #pragma unroll
                for (int ni = 0; ni < 2; ni++) {
                    acc[mi][ni] = __builtin_amdgcn_mfma_f32_16x16x32_bf16(
                        ah, bh[ni], acc[mi][ni], 0, 0, 0);
                    acc[mi][ni] = __builtin_amdgcn_mfma_f32_16x16x32_bf16(
                        ah, bl[ni], acc[mi][ni], 0, 0, 0);
                    acc[mi][ni] = __builtin_amdgcn_mfma_f32_16x16x32_bf16(
                        al, bh[ni], acc[mi][ni], 0, 0, 0);
                }
            }
        }
        __syncthreads();
    }

    float* pb = part + ((size_t)(b * 32 + ch)) * 16384;
    #pragma unroll
    for (int mi = 0; mi < 8; mi++)
        #pragma unroll
        for (int ni = 0; ni < 2; ni++)
            #pragma unroll
            for (int r = 0; r < 4; r++) {
                int c = mi * 16 + (lane >> 4) * 4 + r;
                int d = w * 32 + ni * 16 + (lane & 15);
                pb[c * 128 + d] = acc[mi][ni][r];
            }
}

// ---------------------------------------------------------------------------
// CAM reduce + negated softmax -> bf16, pre-scaled by gamma_cam.
// ---------------------------------------------------------------------------
__global__ __launch_bounds__(128)
void k_cam_reduce(const float* __restrict__ part,
                  const float* __restrict__ gamma_cam, u16* __restrict__ acam16)
{
    const int b = blockIdx.y, c = blockIdx.x;
    const int d = threadIdx.x;
    float s = 0.f;
    for (int ch = 0; ch < 32; ch++)
        s += part[(((size_t)(b * 32 + ch)) * C_ + c) * C_ + d];
    float mn = s;
    #pragma unroll
    for (int off = 32; off; off >>= 1) mn = fminf(mn, __shfl_xor(mn, off));
    __shared__ float m1[2], m2[2];
    if ((d & 63) == 0) m1[d >> 6] = mn;
    __syncthreads();
    mn = fminf(m1[0], m1[1]);
    float p = __expf(mn - s);
    float sum = p;
    #pragma unroll
    for (int off = 32; off; off >>= 1) sum += __shfl_xor(sum, off);
    if ((d & 63) == 0) m2[d >> 6] = sum;
    __syncthreads();
    sum = m2[0] + m2[1];
    acam16[((size_t)(b * C_ + c)) * C_ + d] = f2bf(gamma_cam[0] * p / sum);
}

// ---------------------------------------------------------------------------
// X' = 3x + gt*(TIM t-mix of x) -> bf16. TIM softmax computed inline from e_t.
// ---------------------------------------------------------------------------
__global__ __launch_bounds__(256)
void k_xprime(const float* __restrict__ x, const float* __restrict__ e_t,
              const float* __restrict__ gamma_tim, u16* __restrict__ Xp)
{
    const int b = blockIdx.y, c = blockIdx.x;
    const size_t base = ((size_t)(b * C_ + c)) * P_;
    const int tid = threadIdx.x;
    const float gt = gamma_tim[0];

    float4 xv[8];
    #pragma unroll
    for (int t = 0; t < 8; t++)
        xv[t] = *(const float4*)&x[base + t * HW_ + tid * 4];

    #pragma unroll
    for (int t = 0; t < 8; t++) {
        float e[8];
        #pragma unroll
        for (int s = 0; s < 8; s++) e[s] = e_t[b * 64 + t * 8 + s];
        float mn = e[0];
        #pragma unroll
        for (int s = 1; s < 8; s++) mn = fminf(mn, e[s]);
        float p[8], sum = 0.f;
        #pragma unroll
        for (int s = 0; s < 8; s++) { p[s] = __expf(mn - e[s]); sum += p[s]; }
        float inv = gt / sum;

        float4 o = make_float4(3.f * xv[t].x, 3.f * xv[t].y,
                               3.f * xv[t].z, 3.f * xv[t].w);
        #pragma unroll
        for (int s = 0; s < 8; s++) {
            float wgt = p[s] * inv;
            o.x += wgt * xv[s].x; o.y += wgt * xv[s].y;
            o.z += wgt * xv[s].z; o.w += wgt * xv[s].w;
        }
        ushort4 pk;
        pk.x = f2bf(o.x); pk.y = f2bf(o.y); pk.z = f2bf(o.z); pk.w = f2bf(o.w);
        *(ushort4*)&Xp[base + t * HW_ + tid * 4] = pk;
    }
}

// ---------------------------------------------------------------------------
// CAM AV MFMA + final combine: out = pam16 + acam16 @ x + X'.  Single store.
// ---------------------------------------------------------------------------
__global__ __launch_bounds__(256)
void k_cam_av(const u16* __restrict__ acam16, const u16* __restrict__ xT,
              const u16* __restrict__ Xp, const u16* __restrict__ pam16,
              float* __restrict__ out)
{
    const int b  = blockIdx.y;
    const int p0 = blockIdx.x * 128;
    const int tid = threadIdx.x, lane = tid & 63, w = tid >> 6;

    const u16* Ab = acam16 + (size_t)b * C_ * C_;
    const u16* Bb = xT + ((size_t)(b * P_ + p0 + w * 32)) * C_;

    f32x4 acc[8][2];
    #pragma unroll
    for (int mi = 0; mi < 8; mi++) {
        acc[mi][0] = (f32x4){0.f, 0.f, 0.f, 0.f};
        acc[mi][1] = (f32x4){0.f, 0.f, 0.f, 0.f};
    }

    bf16x8 bg[4][2];
    #pragma unroll
    for (int ks = 0; ks < 4; ks++)
        #pragma unroll
        for (int ni = 0; ni < 2; ni++)
            bg[ks][ni] = *(const bf16x8*)(Bb +
                (size_t)(ni * 16 + (lane & 15)) * C_ + ks * 32 + (lane >> 4) * 8);

    #pragma unroll
    for (int mi = 0; mi < 8; mi++) {
        #pragma unroll
        for (int ks = 0; ks < 4; ks++) {
            bf16x8 af = *(const bf16x8*)(Ab +
                (size_t)(mi * 16 + (lane & 15)) * C_ + ks * 32 + (lane >> 4) * 8);
            acc[mi][0] = __builtin_amdgcn_mfma_f32_16x16x32_bf16(
                af, bg[ks][0], acc[mi][0], 0, 0, 0);
            acc[mi][1] = __builtin_amdgcn_mfma_f32_16x16x32_bf16(
                af, bg[ks][1], acc[mi][1], 0, 0, 0);
        }
    }

    const int tt = p0 >> 10;
    float* ob = out + (size_t)b * C_ * P_;
    const u16* xp = Xp + (size_t)b * C_ * P_;
    const u16* pb = pam16 + (size_t)b * CT_ * HW_;
    #pragma unroll
    for (int mi = 0; mi < 8; mi++)
        #pragma unroll
        for (int ni = 0; ni < 2; ni++)
            #pragma unroll
            for (int r = 0; r < 4; r++) {
                int c = mi * 16 + (lane >> 4) * 4 + r;
                int p = p0 + w * 32 + ni * 16 + (lane & 15);
                int hw = p & 1023;
                size_t i = (size_t)c * P_ + p;
                float pam = bf2f(pb[((size_t)(c * 8 + tt)) * HW_ + hw]);
                ob[i] = pam + acc[mi][ni][r] + bf2f(xp[i]);
            }
}

// ---------------------------------------------------------------------------
extern "C" void kernel_launch(void* const* d_in, const int* in_sizes, int n_in,
                              void* d_out, int out_size, void* d_ws, size_t ws_size,
                              hipStream_t stream)
{
    (void)in_sizes; (void)n_in; (void)out_size; (void)ws_size;
    const float* x  = (const float*)d_in[0];
    const float* Wq = (const float*)d_in[1];
    const float* bq = (const float*)d_in[2];
    const float* Wk = (const float*)d_in[3];
    const float* bk = (const float*)d_in[4];
    const float* Wv = (const float*)d_in[5];
    const float* bv = (const float*)d_in[6];
    const float* gp = (const float*)d_in[7];
    const float* gc = (const float*)d_in[8];
    const float* gt = (const float*)d_in[9];
    float* out = (float*)d_out;
    char*  ws  = (char*)d_ws;

    const size_t MiB = 1u << 20;
    u16*   xT     = (u16*)(ws + 0);            // 16 MiB
    u16*   v16    = (u16*)(ws + 16 * MiB);     // 16 MiB
    u16*   xhi    = (u16*)(ws + 32 * MiB);     // 16 MiB
    u16*   xlo    = (u16*)(ws + 48 * MiB);     // 16 MiB
    u16*   A16    = (u16*)(ws + 64 * MiB);     // 16 MiB
    u16*   pam16  = (u16*)(ws + 80 * MiB);     // 16 MiB
    float* part   = (float*)(ws + 96 * MiB);   // 16.8 MiB
    u16*   Xp16   = (u16*)(ws + 113 * MiB);    // 16 MiB
    u16*   qtb    = (u16*)(ws + 130 * MiB);    // 2 MiB
    u16*   ktb    = (u16*)(ws + 132 * MiB);    // 2 MiB
    u16*   acam16 = (u16*)(ws + 134 * MiB);    // 32 KB
    u16*   Wall   = (u16*)(ws + 134 * MiB + 65536);   // 40 KB
    float* etim   = (float*)(ws + 134 * MiB + 131072);

    hipMemsetAsync(etim, 0, 512 * sizeof(float), stream);

    k_tim_gram  <<<dim3(128, 8),  256, 0, stream>>>(x, etim,                 // 1
                                                    Wq, Wk, Wv, Wall);
    k_prep      <<<dim3(64, 8),   256, 0, stream>>>(x, xT, xhi, xlo, Wall,   // 2
                                                    bq, bk, bv,
                                                    qtb, ktb, v16);
    k_attn      <<<dim3(64, 8),   256, 0, stream>>>(qtb, ktb, A16);          // 3
    k_pv        <<<dim3(8, 8, 8), 256, 0, stream>>>(v16, A16, gp, pam16);    // 4
    k_xprime    <<<dim3(128, 8),  256, 0, stream>>>(x, etim, gt, Xp16);      // 5
    k_cam_gram  <<<dim3(32, 8),   256, 0, stream>>>(xhi, xlo, part);         // 6
    k_cam_reduce<<<dim3(128, 8),  128, 0, stream>>>(part, gc, acam16);       // 7
    k_cam_av    <<<dim3(64, 8),   256, 0, stream>>>(acam16, xT, Xp16,        // 8
                                                    pam16, out);
}